// Round 2
// baseline (192.894 us; speedup 1.0000x reference)
//
#include <hip/hip_runtime.h>

// Problem constants (B=2048, F=512, U=512, G=64, REG_STRENGTH=1.0)
#define B_SZ 2048
#define F_SZ 512
#define U_SZ 512
#define G_SZ 64
#define REG_STRENGTH 1.0f

// One fused kernel, BARRIER-FREE main loop:
//   block = (group g, 64-col n-tile), 256 threads = 4 waves x 16 cols.
//   No LDS staging of X: each wave gathers its own A-fragments straight from
//   global (X = 4 MB, L2-resident per XCD; blocks of a group share an XCD).
//   W (B-operand) loaded per-lane (each lane owns one output column's row of
//   W). fp32 -> bf16 hi/lo split, 3x mfma_f32_16x16x32_bf16 (fp32 accuracy).
//   Waves run fully decoupled after the gid scan -> latency self-hiding.
#define NT 8                 // n-tiles per group (64 cols each)
#define THREADS 256
#define NBLOCKS (NT * G_SZ)  // 512
#define NWAVES (NBLOCKS * 4) // 2048

typedef float f32x4 __attribute__((ext_vector_type(4)));
typedef __bf16 bf16x8 __attribute__((ext_vector_type(8)));

#define MFMA(a, b, c) __builtin_amdgcn_mfma_f32_16x16x32_bf16((a), (b), (c), 0, 0, 0)

// fp32 -> (hi, lo) bf16 split of 8 values. RNE via native casts; dropped
// lo*lo term in the matmul is O(2^-18) -> fp32-grade accuracy.
static __device__ __forceinline__ void cvt8(const f32x4 a, const f32x4 b,
                                            bf16x8& h, bf16x8& l) {
#pragma unroll
  for (int i = 0; i < 4; ++i) {
    const __bf16 hb = (__bf16)a[i];
    h[i] = hb;
    l[i] = (__bf16)(a[i] - (float)hb);
  }
#pragma unroll
  for (int i = 0; i < 4; ++i) {
    const __bf16 hb = (__bf16)b[i];
    h[4 + i] = hb;
    l[4 + i] = (__bf16)(b[i] - (float)hb);
  }
}

__global__ __launch_bounds__(THREADS, 2) void fused_kernel(
    const float* __restrict__ x, const int* __restrict__ gid,
    const float* __restrict__ w_mu, const float* __restrict__ b_mu,
    const float* __restrict__ w0_mu, const float* __restrict__ b0_mu,
    float* __restrict__ out, float* __restrict__ wsf,
    unsigned* __restrict__ done) {
  __shared__ int rows_s[B_SZ];  // 8 KB; only LDS use
  __shared__ int cnt_s;

  // XCD co-location: the 8 n-tile blocks of a group land on one XCD
  // (XCD = linear wg id % 8), sharing gid + x rows in that XCD's L2.
  const int f = blockIdx.x;
  const int r8 = f & 7;
  const int q = f >> 3;                // 0..63
  const int nt = q & 7;                // n-tile 0..7
  const int g = ((q >> 3) << 3) + r8;  // bijective

  const int tid = threadIdx.x;
  const int lane = tid & 63;
  const int wv = tid >> 6;    // wave 0..3 -> 16-col slice
  const int lhi = lane >> 4;  // k-subchunk within fragment (k = 8*lhi + e)
  const int llo = lane & 15;  // row (A) / col (B) within 16-tile

  // ---- per-block gid scan -> row list for this group (order irrelevant) ----
  if (tid == 0) cnt_s = 0;
  __syncthreads();
#pragma unroll
  for (int u = 0; u < 2; ++u) {
    const int4 v = ((const int4*)gid)[tid + u * THREADS];
    const int b0 = (tid + u * THREADS) << 2;
    if (v.x == g) rows_s[atomicAdd(&cnt_s, 1)] = b0;
    if (v.y == g) rows_s[atomicAdd(&cnt_s, 1)] = b0 + 1;
    if (v.z == g) rows_s[atomicAdd(&cnt_s, 1)] = b0 + 2;
    if (v.w == g) rows_s[atomicAdd(&cnt_s, 1)] = b0 + 3;
  }
  __syncthreads();  // last barrier in the kernel
  const int cnt = cnt_s;

  if (cnt > 0) {
    const int mycol = nt * 64 + wv * 16 + llo;  // this lane's output column
    const float* __restrict__ wp =
        w_mu + (size_t)g * (U_SZ * F_SZ) + (size_t)mycol * F_SZ + (lhi << 3);
    const float* __restrict__ w0p = w0_mu + (size_t)mycol * F_SZ + (lhi << 3);

    float regp = 0.0f;
    if (nt == 0) {  // fused bias reg-loss, once per group
      for (int u = tid; u < U_SZ; u += THREADS) {
        const float d = b_mu[(g << 9) + u] - b0_mu[u];
        regp += d * d;
      }
    }

    for (int r0c = 0; r0c < cnt; r0c += 64) {  // executes once (cnt ~ 32)
      const int rc = min(64, cnt - r0c);
      const int mt = (rc + 15) >> 4;  // 16-row m-tiles
      const bool doreg = (r0c == 0);

      // hoist per-m X row pointers (k-invariant); clamp dup rows (not stored)
      const float* xp[4];
#pragma unroll
      for (int m = 0; m < 4; ++m) {
        int r = r0c + (m << 4) + llo;
        if (r >= cnt) r = cnt - 1;
        xp[m] = x + (size_t)rows_s[r] * F_SZ + (lhi << 3);
      }

      f32x4 acc[4];
#pragma unroll
      for (int m = 0; m < 4; ++m) acc[m] = (f32x4){0.f, 0.f, 0.f, 0.f};

      // ---- barrier-free K loop: 16 independent k32 chunks ----
#pragma unroll 4
      for (int kc = 0; kc < F_SZ; kc += 32) {
        const f32x4 wa = *(const f32x4*)(wp + kc);
        const f32x4 wb = *(const f32x4*)(wp + kc + 4);
        if (doreg) {  // fused W reg-loss: each W element visited exactly once
          const f32x4 za = *(const f32x4*)(w0p + kc);
          const f32x4 zb = *(const f32x4*)(w0p + kc + 4);
#pragma unroll
          for (int i = 0; i < 4; ++i) {
            const float d0 = wa[i] - za[i], d1 = wb[i] - zb[i];
            regp += d0 * d0 + d1 * d1;
          }
        }
        bf16x8 wh, wl;
        cvt8(wa, wb, wh, wl);
#pragma unroll
        for (int m = 0; m < 4; ++m) {
          if (m < mt) {
            const f32x4 a0 = *(const f32x4*)(xp[m] + kc);
            const f32x4 a1 = *(const f32x4*)(xp[m] + kc + 4);
            bf16x8 ah, al;
            cvt8(a0, a1, ah, al);
            acc[m] = MFMA(ah, wh, acc[m]);
            acc[m] = MFMA(ah, wl, acc[m]);
            acc[m] = MFMA(al, wh, acc[m]);
          }
        }
      }

      // ---- epilogue: bias + scatter stores (D: row = 4*lhi + j, col = llo) --
      const float bias = b_mu[(g << 9) + mycol];
#pragma unroll
      for (int m = 0; m < 4; ++m) {
        if (m < mt) {
#pragma unroll
          for (int j = 0; j < 4; ++j) {
            const int rl = (m << 4) + (lhi << 2) + j;
            if (rl < rc) {
              out[(size_t)rows_s[r0c + rl] * U_SZ + mycol] = acc[m][j] + bias;
            }
          }
        }
      }
    }

    // ---- wave-level reduce of reg partials, weight by cnt, one atomic ----
#pragma unroll
    for (int o = 32; o > 0; o >>= 1) regp += __shfl_down(regp, o, 64);
    if (lane == 0) atomicAdd(wsf, (float)cnt * regp);
  }

  // fused finalize: last WAVE to finish writes the reg-loss scalar
  if (lane == 0) {
    __threadfence();
    const unsigned prev = atomicAdd(done, 1u);
    if (prev == (unsigned)(NWAVES - 1)) {
      const float v = atomicAdd(wsf, 0.0f);  // coherent device-scope read
      out[(size_t)B_SZ * U_SZ] = REG_STRENGTH * v;
    }
  }
}

extern "C" void kernel_launch(void* const* d_in, const int* in_sizes, int n_in,
                              void* d_out, int out_size, void* d_ws,
                              size_t ws_size, hipStream_t stream) {
  (void)in_sizes; (void)n_in; (void)out_size; (void)ws_size;
  const float* x     = (const float*)d_in[0];
  const int*   gid   = (const int*)d_in[1];
  const float* w_mu  = (const float*)d_in[2];
  const float* b_mu  = (const float*)d_in[3];
  const float* w0_mu = (const float*)d_in[4];
  const float* b0_mu = (const float*)d_in[5];

  float* wsf = (float*)d_ws;
  unsigned* done = (unsigned*)d_ws + 1;

  hipMemsetAsync(d_ws, 0, 8, stream);
  fused_kernel<<<NBLOCKS, THREADS, 0, stream>>>(x, gid, w_mu, b_mu, w0_mu,
                                                b0_mu, (float*)d_out, wsf, done);
}